// Round 1
// 2036.558 us; speedup vs baseline: 1.6485x; 1.6485x over previous
//
#include <hip/hip_runtime.h>
#include <hip/hip_bf16.h>
#include <hip/hip_fp16.h>

// Problem: B=64, T=1024, INPUT=256, HIDDEN=512, OUTPUT=256
//   xh = x @ W_xh + b_h
//   h_t = tanh(h_{t-1} @ W_hh + xh_t)   (serial over t)
//   out = hs @ W_hy + b_y
//
// Round 3 changes vs round 2:
//  - scan: 7/16 streamed weight uint4s cached in LDS (57 KiB) -> L2 stream
//    drops 128->72 KiB/step; early chunks get deterministic LDS latency.
//  - scan: quad reduce via DPP quad_perm (VALU) instead of ds_swizzle (LDS pipe).
//  - scan: fast tanh = 1 - 2*rcp(exp2(2x*log2e)+1)  (v_exp + v_rcp).
//  - GEMM2 (hs @ W_hy): packed f16 dot2 inner loop (2 MAC/instr). GEMM1 kept
//    f32 (its error feeds the recurrence; absmax headroom is small).

#define BT 65536      // B*T
#define HID 512
#define NIN 256
#define NOUT 256
#define TSTEPS 1024
#define NBATCH 64

typedef _Float16 hf2_t __attribute__((ext_vector_type(2)));

__device__ __forceinline__ float fdot2(unsigned w, unsigned h, float acc) {
#if __has_builtin(__builtin_amdgcn_fdot2)
    return __builtin_amdgcn_fdot2(__builtin_bit_cast(hf2_t, w),
                                  __builtin_bit_cast(hf2_t, h), acc, false);
#else
    __half2 wv = __builtin_bit_cast(__half2, w);
    __half2 hv = __builtin_bit_cast(__half2, h);
    float2 wf = __half22float2(wv);
    float2 hf = __half22float2(hv);
    return acc + wf.x * hf.x + wf.y * hf.y;
#endif
}

__device__ __forceinline__ float dot4(uint4 w, uint4 h, float acc) {
    acc = fdot2(w.x, h.x, acc);
    acc = fdot2(w.y, h.y, acc);
    acc = fdot2(w.z, h.z, acc);
    acc = fdot2(w.w, h.w, acc);
    return acc;
}

__device__ __forceinline__ unsigned pack2h(float a, float b) {
    unsigned lo = (unsigned)__half_as_ushort(__float2half_rn(a));
    unsigned hi = (unsigned)__half_as_ushort(__float2half_rn(b));
    return lo | (hi << 16);
}

// cross-lane add within aligned quads via DPP quad_perm (VALU pipe, no LDS)
template <int CTRL>
__device__ __forceinline__ float dpp_add(float x) {
    int y = __builtin_amdgcn_mov_dpp(__float_as_int(x), CTRL, 0xF, 0xF, true);
    return x + __int_as_float(y);
}

// tanh(x) = 1 - 2/(e^{2x}+1); e^{2x} via v_exp_f32, division via v_rcp_f32.
// Saturates correctly for |x| large (inf -> 1, 0 -> -1). ~1e-6 abs error.
__device__ __forceinline__ float fast_tanh(float x) {
    float e = __builtin_amdgcn_exp2f(x * 2.8853900817779268f);   // 2*log2(e)
    return 1.0f - 2.0f * __builtin_amdgcn_rcpf(e + 1.0f);
}

// ---------- generic load/store helpers ----------
__device__ __forceinline__ float4 load4f(const float* p) {
    return *(const float4*)p;
}
__device__ __forceinline__ float4 load4f(const __half* p) {
    ushort4 u = *(const ushort4*)p;
    float4 r;
    r.x = __half2float(__ushort_as_half(u.x));
    r.y = __half2float(__ushort_as_half(u.y));
    r.z = __half2float(__ushort_as_half(u.z));
    r.w = __half2float(__ushort_as_half(u.w));
    return r;
}
__device__ __forceinline__ void store1(float* p, float v) { *p = v; }
__device__ __forceinline__ void store1(__half* p, float v) { *p = __float2half_rn(v); }

// ---------- pack W_hh (f32 [k][j]) into per-thread f16 blobs ----------
// Thread t of the scan kernel: q=t>>2, s=t&3, k-range [128s,128s+128),
// columns 4q..4q+3. Cols 0-2 -> reg_blob[i][t] (i=0..47 uint4, coalesced),
// col 3 -> gcol_blob[j][t] (j=0..15 uint4; scan caches j<7 in LDS).
__global__ __launch_bounds__(256)
void pack_w_kernel(const float* __restrict__ W,
                   unsigned* __restrict__ reg_blob,
                   unsigned* __restrict__ gcol_blob) {
    int t = blockIdx.x;      // 0..511  (scan thread id)
    int w = threadIdx.x;     // 0..255  (word index)
    int q = t >> 2, s = t & 3, k0 = 128 * s;
    if (w < 192) {
        int c = w >> 6, m = w & 63;
        int col = 4 * q + c, k = k0 + 2 * m;
        unsigned val = pack2h(W[(size_t)k * HID + col], W[(size_t)(k + 1) * HID + col]);
        int i = w >> 2, u = w & 3;
        reg_blob[i * 2048 + t * 4 + u] = val;
    } else {
        int m = w - 192;                       // 0..63
        int col = 4 * q + 3, k = k0 + 2 * m;
        unsigned val = pack2h(W[(size_t)k * HID + col], W[(size_t)(k + 1) * HID + col]);
        int j = m >> 2, u = m & 3;
        gcol_blob[j * 2048 + t * 4 + u] = val;
    }
}

// ---------- f32 tiled GEMM with bias: C[M,N] = A[M,K] @ B[K,N] + bias[N] ----------
// Used only for xh = x @ W_xh + b_h (precision feeds the recurrence).
template <typename AT, typename CT>
__global__ __launch_bounds__(256)
void gemm_bias_kernel(const AT* __restrict__ A, const float* __restrict__ B,
                      const float* __restrict__ bias, CT* __restrict__ C,
                      int M, int N, int K) {
    const int TM = 64, TN = 64, TK = 16;
    __shared__ float As[TK][TM];
    __shared__ float Bs[TK][TN + 4];

    int tid = threadIdx.x;
    int tx = tid & 15;
    int ty = tid >> 4;
    int row0 = blockIdx.x * TM;
    int col0 = blockIdx.y * TN;

    float c[4][4];
#pragma unroll
    for (int i = 0; i < 4; ++i)
#pragma unroll
        for (int j = 0; j < 4; ++j) c[i][j] = 0.f;

    for (int kk = 0; kk < K; kk += TK) {
        {
            int ar = tid >> 2;
            int ac = (tid & 3) * 4;
            float4 av = load4f(A + (size_t)(row0 + ar) * K + kk + ac);
            As[ac + 0][ar] = av.x;
            As[ac + 1][ar] = av.y;
            As[ac + 2][ar] = av.z;
            As[ac + 3][ar] = av.w;
        }
        {
            int br = tid >> 4;
            int bc = (tid & 15) * 4;
            float4 bv = *(const float4*)(B + (size_t)(kk + br) * N + col0 + bc);
            *(float4*)&Bs[br][bc] = bv;
        }
        __syncthreads();
#pragma unroll
        for (int k = 0; k < TK; ++k) {
            float4 a = *(const float4*)&As[k][ty * 4];
            float4 b = *(const float4*)&Bs[k][tx * 4];
            float av[4] = {a.x, a.y, a.z, a.w};
            float bv[4] = {b.x, b.y, b.z, b.w};
#pragma unroll
            for (int i = 0; i < 4; ++i)
#pragma unroll
                for (int j = 0; j < 4; ++j) c[i][j] += av[i] * bv[j];
        }
        __syncthreads();
    }

#pragma unroll
    for (int j = 0; j < 4; ++j) {
        float bb = bias[col0 + tx * 4 + j];
#pragma unroll
        for (int i = 0; i < 4; ++i) {
            int r = row0 + ty * 4 + i;
            int cc = col0 + tx * 4 + j;
            store1(&C[(size_t)r * N + cc], c[i][j] + bb);
        }
    }
}

// ---------- packed-f16 dot2 GEMM with bias (2 MACs/instr) ----------
// Used for out = hs @ W_hy + b_y: A is already f16, W_hy rounding adds ~4e-4
// absolute to out and does NOT feed back into the recurrence.
template <typename AT, typename CT>
__global__ __launch_bounds__(256)
void gemm_bias_f16_kernel(const AT* __restrict__ A, const float* __restrict__ B,
                          const float* __restrict__ bias, CT* __restrict__ C,
                          int M, int N, int K) {
    const int TM = 64, TN = 64, TK = 16;
    __shared__ unsigned Asp[TK / 2][TM];       // pack(A[m][2k2], A[m][2k2+1])
    __shared__ unsigned Bsp[TK / 2][TN + 4];   // pack(B[2k2][n], B[2k2+1][n]); 272B rows keep 16B align

    int tid = threadIdx.x;
    int tx = tid & 15;
    int ty = tid >> 4;
    int row0 = blockIdx.x * TM;
    int col0 = blockIdx.y * TN;

    float c[4][4];
#pragma unroll
    for (int i = 0; i < 4; ++i)
#pragma unroll
        for (int j = 0; j < 4; ++j) c[i][j] = 0.f;

    for (int kk = 0; kk < K; kk += TK) {
        {   // A: 64 rows x 16 k; thread loads 4 consecutive k of one row
            int ar = tid >> 2;             // 0..63
            int ac = (tid & 3) * 4;        // 0,4,8,12
            float4 av = load4f(A + (size_t)(row0 + ar) * K + kk + ac);
            Asp[(ac >> 1) + 0][ar] = pack2h(av.x, av.y);
            Asp[(ac >> 1) + 1][ar] = pack2h(av.z, av.w);
        }
        {   // B: 16 k x 64 n; thread packs one k-pair for 2 columns
            int k2 = tid >> 5;             // 0..7
            int bc = (tid & 31) * 2;       // 0..62
            const float* b0 = B + (size_t)(kk + 2 * k2) * N + col0 + bc;
            const float* b1 = b0 + N;
            float2 r0 = *(const float2*)b0;
            float2 r1 = *(const float2*)b1;
            Bsp[k2][bc + 0] = pack2h(r0.x, r1.x);
            Bsp[k2][bc + 1] = pack2h(r0.y, r1.y);
        }
        __syncthreads();
#pragma unroll
        for (int k2 = 0; k2 < TK / 2; ++k2) {
            uint4 ap = *(const uint4*)&Asp[k2][ty * 4];
            uint4 bp = *(const uint4*)&Bsp[k2][tx * 4];
            unsigned av[4] = {ap.x, ap.y, ap.z, ap.w};
            unsigned bv[4] = {bp.x, bp.y, bp.z, bp.w};
#pragma unroll
            for (int i = 0; i < 4; ++i)
#pragma unroll
                for (int j = 0; j < 4; ++j) c[i][j] = fdot2(av[i], bv[j], c[i][j]);
        }
        __syncthreads();
    }

#pragma unroll
    for (int j = 0; j < 4; ++j) {
        float bb = bias[col0 + tx * 4 + j];
#pragma unroll
        for (int i = 0; i < 4; ++i) {
            int r = row0 + ty * 4 + i;
            int cc = col0 + tx * 4 + j;
            store1(&C[(size_t)r * N + cc], c[i][j] + bb);
        }
    }
}

// ---------- scan: one WG (one CU) per batch row, no inter-WG traffic ----------
// streamed-column uint4s j=0..6 cached in LDS (57 KiB); j=7..15 from L2.
#define GETG(j) (((j) < 7) ? gl[(j) % 7][t] : gb[(size_t)(j) * 512])

__global__ __launch_bounds__(512, 2)
void rnn_scan_single(const __half* __restrict__ xh,
                     const uint4* __restrict__ reg_blob,    // [48][512]
                     const uint4* __restrict__ gcol_blob,   // [16][512]
                     __half* __restrict__ hs) {
    // h double-buffered; 272B slice stride keeps the 4 per-wave broadcast
    // addresses on disjoint bank quads.
    __shared__ __align__(16) __half hbuf[2][4][136];
    __shared__ uint4 gl[7][512];   // 57,344 B; total static LDS = 59,520 B < 64 KiB

    const int t = threadIdx.x;
    const int b = blockIdx.x;
    const int s = t & 3;

    // 192 VGPRs of weights: columns 4q+0..2, k in [128s, 128s+128)
    uint4 W[48];
#pragma unroll
    for (int i = 0; i < 48; ++i) W[i] = reg_blob[i * 512 + t];
    // cache first 7 streamed uint4s per thread in LDS (coalesced, conflict-free)
#pragma unroll
    for (int j = 0; j < 7; ++j) gl[j][t] = gcol_blob[j * 512 + t];

    hbuf[0][t >> 7][t & 127] = __ushort_as_half((unsigned short)0);
    hbuf[1][t >> 7][t & 127] = __ushort_as_half((unsigned short)0);
    __syncthreads();

    const __half* xp = xh + (size_t)b * TSTEPS * HID + t;
    __half* hp = hs + (size_t)b * TSTEPS * HID + t;
    const uint4* gb = gcol_blob + t;

    int cur = 0;
    __half prev = __ushort_as_half((unsigned short)0);

    for (int step = 0; step < TSTEPS; ++step) {
        float xv = __half2float(xp[(size_t)step * HID]);   // issued early, used late
        if (step) hp[(size_t)(step - 1) * HID] = prev;     // delayed store: far from barrier

        const uint4* hv = (const uint4*)&hbuf[cur][s][0];
        float a0 = 0.f, a1 = 0.f, a2 = 0.f, a3 = 0.f;

        // streamed column (col 4q+3): LDS for j<7, L2 for j>=7, chunked with
        // register-column dots
#pragma unroll
        for (int ch = 0; ch < 4; ++ch) {
            uint4 g0 = GETG(ch * 4 + 0);
            uint4 g1 = GETG(ch * 4 + 1);
            uint4 g2 = GETG(ch * 4 + 2);
            uint4 g3 = GETG(ch * 4 + 3);
            uint4 h0 = hv[ch * 4 + 0];
            uint4 h1 = hv[ch * 4 + 1];
            uint4 h2 = hv[ch * 4 + 2];
            uint4 h3 = hv[ch * 4 + 3];
            a0 = dot4(W[ch * 4 + 0], h0, a0);
            a1 = dot4(W[16 + ch * 4 + 0], h0, a1);
            a2 = dot4(W[32 + ch * 4 + 0], h0, a2);
            a0 = dot4(W[ch * 4 + 1], h1, a0);
            a1 = dot4(W[16 + ch * 4 + 1], h1, a1);
            a2 = dot4(W[32 + ch * 4 + 1], h1, a2);
            a0 = dot4(W[ch * 4 + 2], h2, a0);
            a1 = dot4(W[16 + ch * 4 + 2], h2, a1);
            a2 = dot4(W[32 + ch * 4 + 2], h2, a2);
            a0 = dot4(W[ch * 4 + 3], h3, a0);
            a1 = dot4(W[16 + ch * 4 + 3], h3, a1);
            a2 = dot4(W[32 + ch * 4 + 3], h3, a2);
            a3 = dot4(g0, h0, a3);
            a3 = dot4(g1, h1, a3);
            a3 = dot4(g2, h2, a3);
            a3 = dot4(g3, h3, a3);
        }

        // reduce across the 4 k-slices (aligned quads) on the VALU via DPP
        a0 = dpp_add<0xB1>(a0); a0 = dpp_add<0x4E>(a0);
        a1 = dpp_add<0xB1>(a1); a1 = dpp_add<0x4E>(a1);
        a2 = dpp_add<0xB1>(a2); a2 = dpp_add<0x4E>(a2);
        a3 = dpp_add<0xB1>(a3); a3 = dpp_add<0x4E>(a3);
        float tot = (s == 0) ? a0 : (s == 1) ? a1 : (s == 2) ? a2 : a3;

        float hn = fast_tanh(tot + xv);
        prev = __float2half_rn(hn);
        hbuf[cur ^ 1][t >> 7][t & 127] = prev;
        __syncthreads();
        cur ^= 1;
    }
    hp[(size_t)(TSTEPS - 1) * HID] = prev;
}

extern "C" void kernel_launch(void* const* d_in, const int* in_sizes, int n_in,
                              void* d_out, int out_size, void* d_ws, size_t ws_size,
                              hipStream_t stream) {
    const float* x    = (const float*)d_in[0];   // [64,1024,256]
    const float* W_xh = (const float*)d_in[1];   // [256,512]
    const float* W_hh = (const float*)d_in[2];   // [512,512]
    const float* b_h  = (const float*)d_in[3];   // [512]
    const float* W_hy = (const float*)d_in[4];   // [512,256]
    const float* b_y  = (const float*)d_in[5];   // [256]
    float* out = (float*)d_out;                  // [64,1024,256]

    char* ws = (char*)d_ws;
    const size_t off_gcol = 48 * 512 * 16;                  // 384 KiB
    const size_t off_xh   = (size_t)1 << 20;                // 1 MiB
    const size_t off_hs   = off_xh + (size_t)BT * HID * 2;  // +64 MiB

    unsigned* reg_blob  = (unsigned*)ws;
    unsigned* gcol_blob = (unsigned*)(ws + off_gcol);
    __half*   xh        = (__half*)(ws + off_xh);
    __half*   hs        = (__half*)(ws + off_hs);

    // 1) pack W_hh -> per-thread f16 blobs
    pack_w_kernel<<<dim3(512), dim3(256), 0, stream>>>(W_hh, reg_blob, gcol_blob);

    // 2) xh = x @ W_xh + b_h   (f32 math -> f16 C; feeds the recurrence)
    gemm_bias_kernel<float, __half>
        <<<dim3(BT / 64, HID / 64), dim3(256), 0, stream>>>(x, W_xh, b_h, xh, BT, HID, NIN);

    // 3) scan: 64 WGs, one per batch row, zero cross-WG traffic
    rnn_scan_single<<<dim3(NBATCH), dim3(512), 0, stream>>>(
        xh, (const uint4*)reg_blob, (const uint4*)gcol_blob, hs);

    // 4) out = hs @ W_hy + b_y   (packed f16 dot2; error does not recurse)
    gemm_bias_f16_kernel<__half, float>
        <<<dim3(BT / 64, NOUT / 64), dim3(256), 0, stream>>>(hs, W_hy, b_y, out, BT, NOUT, HID);
}